// Round 5
// baseline (379.377 us; speedup 1.0000x reference)
//
#include <hip/hip_runtime.h>
#include <stdint.h>

// (B,C,H,W)=(4,128,64,128), R=4, D=9, out channels 81.
// out[b, di*9+dj, h, w] = sum_c src[b,c,h,w] * tgt[b,c,h+di-8,w+dj-8]
// (zero when shifted index leaves [0,H)x[0,W)).
//
// Block = (b, 4 src rows, 32-channel quarter). grid = 16 hg x (4 b x 4 cq) = 256.
// 576 threads = 9 waves; wave w == di. Within wave: r=(tid>>4)&3, ql=tid&15.
// A 16-lane group owns one (h=h0+r, di) output row; lane ql owns cols [8ql,8ql+8).
// Halo (8 cols to the left) comes from the previous lane via DPP row_shr:1
// (bound_ctrl zeros lane 0 of each 16-row = true image left boundary).
// LDS: per 4-ch chunk, tgt rows [h0-8,h0+4) + src rows, stride padded to 132
// floats -> minimal bank multiplicity (conflict-free). Double-buffered.
// 4 channel-quarter blocks accumulate into out via fp32 global atomics
// (out zeroed by hipMemsetAsync first).
#define NB 4
#define NC 128
#define NH 64
#define NW 128
#define ND 9
#define NOUT 81

#define NHB 4                  // src rows per block
#define CQ 32                  // channels per block
#define CCH 4                  // channels per chunk
#define NCHUNK (CQ / CCH)      // 8
#define TROWS (NHB + 8)        // 12 tgt rows
#define LSTR 132               // padded LDS row stride (floats)
#define TGT_FL (CCH * TROWS * LSTR)  // 6336
#define SRC_FL (CCH * NHB * LSTR)    // 2112
#define SRC_OFF TGT_FL
#define BUF_FL (TGT_FL + SRC_FL)     // 8448 floats = 33792 B per buffer
#define TGT_F4 (CCH * TROWS * 32)    // 1536 staging float4s
#define ALL_F4 (TGT_F4 + CCH * NHB * 32)  // 2048

__device__ __forceinline__ float prev_lane(float x) {
  // value of lane (l-1) within each 16-lane DPP row; 0 for row-lane 0.
  int yi = __builtin_amdgcn_update_dpp(0, __float_as_int(x), 0x111, 0xf, 0xf, true);
  return __int_as_float(yi);
}

__device__ __forceinline__ void atomic_fadd(float* p, float v) {
#if defined(__has_builtin) && __has_builtin(__builtin_amdgcn_global_atomic_fadd_f32)
  __builtin_amdgcn_global_atomic_fadd_f32(p, v);
#else
  atomicAdd(p, v);
#endif
}

__global__ __launch_bounds__(576, 1)
void costvol_kernel(const float* __restrict__ src,
                    const float* __restrict__ tgt,
                    float* __restrict__ out) {
  __shared__ float lds[2][BUF_FL];

  const int tid = threadIdx.x;
  const int bid = blockIdx.x;
  const int hg = bid >> 4;          // 0..15  (h-adjacent blocks 16 apart -> same XCD)
  const int bc = bid & 15;
  const int b  = bc >> 2;           // 0..3
  const int cq = bc & 3;            // 0..3
  const int h0 = hg * NHB;
  const int c0 = cq * CQ;

  const int di = tid >> 6;          // 0..8 (wave id)
  const int r  = (tid >> 4) & 3;    // row within block
  const int ql = tid & 15;          // lane within 16-group; cols [8ql, 8ql+8)

  float acc[ND][8];
#pragma unroll
  for (int dj = 0; dj < ND; ++dj)
#pragma unroll
    for (int p = 0; p < 8; ++p) acc[dj][p] = 0.0f;

  float4 sreg[4];

  // flat f4 index j in [0,2048): j<1536 -> tgt (ch=j/384, row=(j%384)/32, q=j%32,
  // global row y=h0-8+row, zero-filled when y<0); else src (ch, row, q).
  auto load_regs = [&](int chunk) {
    const int cb = c0 + chunk * CCH;
#pragma unroll
    for (int p = 0; p < 4; ++p) {
      const int j = tid + p * 576;
      if (j < ALL_F4) {
        float4 v = make_float4(0.f, 0.f, 0.f, 0.f);
        if (j < TGT_F4) {
          const int ch = j / 384;
          const int rem = j - ch * 384;
          const int row = rem >> 5;
          const int q = rem & 31;
          const int y = h0 - 8 + row;            // <= h0+3 <= 63
          if (y >= 0)
            v = *(const float4*)(tgt + (size_t)(((b * NC + cb + ch) * NH + y) * NW + 4 * q));
        } else {
          const int k2 = j - TGT_F4;
          const int ch = k2 >> 7;
          const int rem = k2 & 127;
          const int row = rem >> 5;
          const int q = rem & 31;
          v = *(const float4*)(src + (size_t)(((b * NC + cb + ch) * NH + h0 + row) * NW + 4 * q));
        }
        sreg[p] = v;
      }
    }
  };

  auto write_lds = [&](int buf) {
#pragma unroll
    for (int p = 0; p < 4; ++p) {
      const int j = tid + p * 576;
      if (j < ALL_F4) {
        float* dst;
        if (j < TGT_F4) {
          const int ch = j / 384;
          const int rem = j - ch * 384;
          const int row = rem >> 5;
          const int q = rem & 31;
          dst = &lds[buf][(ch * TROWS + row) * LSTR + 4 * q];
        } else {
          const int k2 = j - TGT_F4;
          const int ch = k2 >> 7;
          const int rem = k2 & 127;
          const int row = rem >> 5;
          const int q = rem & 31;
          dst = &lds[buf][SRC_OFF + (ch * NHB + row) * LSTR + 4 * q];
        }
        *(float4*)dst = sreg[p];
      }
    }
  };

  load_regs(0);
  write_lds(0);
  int cur = 0;

  for (int k = 0; k < NCHUNK; ++k) {
    __syncthreads();                       // buf[cur] ready; buf[cur^1] free
    if (k + 1 < NCHUNK) load_regs(k + 1);  // globals in flight during compute

    {
      const float* Lt = &lds[cur][(r + di) * LSTR + 8 * ql];
      const float* Ls = &lds[cur][SRC_OFF + r * LSTR + 8 * ql];
#pragma unroll
      for (int ch = 0; ch < CCH; ++ch) {
        const float4 ta = *(const float4*)(Lt + ch * (TROWS * LSTR));
        const float4 tb = *(const float4*)(Lt + ch * (TROWS * LSTR) + 4);
        const float4 sa = *(const float4*)(Ls + ch * (NHB * LSTR));
        const float4 sb = *(const float4*)(Ls + ch * (NHB * LSTR) + 4);
        float w16[16];
        w16[8]  = ta.x; w16[9]  = ta.y; w16[10] = ta.z; w16[11] = ta.w;
        w16[12] = tb.x; w16[13] = tb.y; w16[14] = tb.z; w16[15] = tb.w;
#pragma unroll
        for (int i = 0; i < 8; ++i) w16[i] = prev_lane(w16[8 + i]);
        float s[8] = {sa.x, sa.y, sa.z, sa.w, sb.x, sb.y, sb.z, sb.w};
#pragma unroll
        for (int dj = 0; dj < ND; ++dj)
#pragma unroll
          for (int p = 0; p < 8; ++p)
            acc[dj][p] = fmaf(s[p], w16[p + dj], acc[dj][p]);
      }
    }

    if (k + 1 < NCHUNK) write_lds(cur ^ 1);  // waits only on its own globals
    cur ^= 1;
  }

  // Epilogue: accumulate the channel-quarter partial into out (zero-inited).
  // Groups with y = h0+r+di-8 < 0 contribute nothing (memset already wrote 0).
  if (h0 + r + di >= 8) {
#pragma unroll
    for (int dj = 0; dj < ND; ++dj) {
      float* op = out + (size_t)(((b * NOUT + di * ND + dj) * NH + h0 + r) * NW + 8 * ql);
#pragma unroll
      for (int p = 0; p < 8; ++p) atomic_fadd(op + p, acc[dj][p]);
    }
  }
}

extern "C" void kernel_launch(void* const* d_in, const int* in_sizes, int n_in,
                              void* d_out, int out_size, void* d_ws, size_t ws_size,
                              hipStream_t stream) {
  const float* src = (const float*)d_in[0];
  const float* tgt = (const float*)d_in[1];
  float* out = (float*)d_out;
  hipMemsetAsync(d_out, 0, (size_t)out_size * sizeof(float), stream);
  costvol_kernel<<<dim3(256), dim3(576), 0, stream>>>(src, tgt, out);
}

// Round 6
// 136.495 us; speedup vs baseline: 2.7794x; 2.7794x over previous
//
#include <hip/hip_runtime.h>
#include <stdint.h>

// (B,C,H,W)=(4,128,64,128), R=4, D=9, out channels 81.
// out[b, di*9+dj, h, w] = sum_c src[b,c,h,w] * tgt[b,c,h+di-8,w+dj-8]
// (zero when shifted index leaves [0,H)x[0,W)).
//
// Two-stage (no atomics):
//  stage1: 256 blocks = hg(16) x b(4) x cq(4); each block computes the
//          32-channel partial for a 4-row band, all 9x9 offsets, and stores
//          it to d_ws with plain float4 stores.
//          Compute core (verified R5, SQ_LDS_BANK_CONFLICT=0): wave==di,
//          16-lane row groups, 8 px/lane, left halo via DPP row_shr:1,
//          LDS stride 132.
//  stage2: out = sum of the 4 quarter partials (pure memory-bound).
#define NB 4
#define NC 128
#define NH 64
#define NW 128
#define HW (NH * NW)
#define ND 9
#define NOUT 81
#define NQ 4
#define QS (NB * NOUT * HW)    // floats per quarter partial = 2,654,208

#define NHB 4                  // src rows per block
#define CQ 32                  // channels per block
#define CCH 4                  // channels per chunk
#define NCHUNK (CQ / CCH)      // 8
#define TROWS (NHB + 8)        // 12 tgt rows
#define LSTR 132               // padded LDS row stride (floats)
#define TGT_FL (CCH * TROWS * LSTR)       // 6336
#define SRC_FL (CCH * NHB * LSTR)         // 2112
#define SRC_OFF TGT_FL
#define BUF_FL (TGT_FL + SRC_FL)          // 8448 floats / buffer
#define TGT_F4 (CCH * TROWS * 32)         // 1536
#define ALL_F4 (TGT_F4 + CCH * NHB * 32)  // 2048

__device__ __forceinline__ float prev_lane(float x) {
  // value of lane (l-1) within each 16-lane DPP row; 0 for row-lane 0.
  int yi = __builtin_amdgcn_update_dpp(0, __float_as_int(x), 0x111, 0xf, 0xf, true);
  return __int_as_float(yi);
}

__global__ __launch_bounds__(576, 1)
void costvol_stage1(const float* __restrict__ src,
                    const float* __restrict__ tgt,
                    float* __restrict__ ws) {
  __shared__ float lds[2][BUF_FL];

  const int tid = threadIdx.x;
  const int bid = blockIdx.x;
  const int hg = bid >> 4;          // 0..15 (hg-adjacent blocks 16 apart -> same XCD)
  const int bc = bid & 15;
  const int b  = bc >> 2;
  const int cq = bc & 3;
  const int h0 = hg * NHB;
  const int c0 = cq * CQ;

  const int di = tid >> 6;          // 0..8 (wave id)
  const int r  = (tid >> 4) & 3;    // row within block
  const int ql = tid & 15;          // 16-lane group lane; cols [8ql, 8ql+8)

  float acc[ND][8];
#pragma unroll
  for (int dj = 0; dj < ND; ++dj)
#pragma unroll
    for (int p = 0; p < 8; ++p) acc[dj][p] = 0.0f;

  float4 sreg[4];

  auto load_regs = [&](int chunk) {
    const int cb = c0 + chunk * CCH;
#pragma unroll
    for (int p = 0; p < 4; ++p) {
      const int j = tid + p * 576;
      if (j < ALL_F4) {
        float4 v = make_float4(0.f, 0.f, 0.f, 0.f);
        if (j < TGT_F4) {
          const int ch = j / 384;
          const int rem = j - ch * 384;
          const int row = rem >> 5;
          const int q = rem & 31;
          const int y = h0 - 8 + row;          // <= 63 always
          if (y >= 0)
            v = *(const float4*)(tgt + (size_t)(((b * NC + cb + ch) * NH + y) * NW + 4 * q));
        } else {
          const int k2 = j - TGT_F4;
          const int ch = k2 >> 7;
          const int rem = k2 & 127;
          const int row = rem >> 5;
          const int q = rem & 31;
          v = *(const float4*)(src + (size_t)(((b * NC + cb + ch) * NH + h0 + row) * NW + 4 * q));
        }
        sreg[p] = v;
      }
    }
  };

  auto write_lds = [&](int buf) {
#pragma unroll
    for (int p = 0; p < 4; ++p) {
      const int j = tid + p * 576;
      if (j < ALL_F4) {
        float* dst;
        if (j < TGT_F4) {
          const int ch = j / 384;
          const int rem = j - ch * 384;
          const int row = rem >> 5;
          const int q = rem & 31;
          dst = &lds[buf][(ch * TROWS + row) * LSTR + 4 * q];
        } else {
          const int k2 = j - TGT_F4;
          const int ch = k2 >> 7;
          const int rem = k2 & 127;
          const int row = rem >> 5;
          const int q = rem & 31;
          dst = &lds[buf][SRC_OFF + (ch * NHB + row) * LSTR + 4 * q];
        }
        *(float4*)dst = sreg[p];
      }
    }
  };

  load_regs(0);
  write_lds(0);
  int cur = 0;

  for (int k = 0; k < NCHUNK; ++k) {
    __syncthreads();                       // buf[cur] ready; buf[cur^1] free
    if (k + 1 < NCHUNK) load_regs(k + 1);  // globals in flight during compute

    {
      const float* Lt = &lds[cur][(r + di) * LSTR + 8 * ql];
      const float* Ls = &lds[cur][SRC_OFF + r * LSTR + 8 * ql];
#pragma unroll
      for (int ch = 0; ch < CCH; ++ch) {
        const float4 ta = *(const float4*)(Lt + ch * (TROWS * LSTR));
        const float4 tb = *(const float4*)(Lt + ch * (TROWS * LSTR) + 4);
        const float4 sa = *(const float4*)(Ls + ch * (NHB * LSTR));
        const float4 sb = *(const float4*)(Ls + ch * (NHB * LSTR) + 4);
        float w16[16];
        w16[8]  = ta.x; w16[9]  = ta.y; w16[10] = ta.z; w16[11] = ta.w;
        w16[12] = tb.x; w16[13] = tb.y; w16[14] = tb.z; w16[15] = tb.w;
#pragma unroll
        for (int i = 0; i < 8; ++i) w16[i] = prev_lane(w16[8 + i]);
        float s[8] = {sa.x, sa.y, sa.z, sa.w, sb.x, sb.y, sb.z, sb.w};
#pragma unroll
        for (int dj = 0; dj < ND; ++dj)
#pragma unroll
          for (int p = 0; p < 8; ++p)
            acc[dj][p] = fmaf(s[p], w16[p + dj], acc[dj][p]);
      }
    }

    if (k + 1 < NCHUNK) write_lds(cur ^ 1);  // waits only on its own globals
    cur ^= 1;
  }

  // Epilogue: plain coalesced stores of the quarter partial (zeros included —
  // stage2 reads every slot, so every slot must be written).
#pragma unroll
  for (int dj = 0; dj < ND; ++dj) {
    float* op = ws + (size_t)cq * QS
              + (size_t)(((b * NOUT + di * ND + dj) * NH + h0 + r) * NW + 8 * ql);
    float4 o0, o1;
    o0.x = acc[dj][0]; o0.y = acc[dj][1]; o0.z = acc[dj][2]; o0.w = acc[dj][3];
    o1.x = acc[dj][4]; o1.y = acc[dj][5]; o1.z = acc[dj][6]; o1.w = acc[dj][7];
    *(float4*)op = o0;
    *(float4*)(op + 4) = o1;
  }
}

// out = ws[q0] + ws[q1] + ws[q2] + ws[q3], float4 per thread.
// grid = QS / (256*4) = 2592 blocks exactly.
__global__ __launch_bounds__(256)
void costvol_reduce(const float* __restrict__ ws, float* __restrict__ out) {
  const size_t i = ((size_t)blockIdx.x * 256 + threadIdx.x) * 4;
  const float4 a = *(const float4*)(ws + i);
  const float4 b = *(const float4*)(ws + (size_t)QS + i);
  const float4 c = *(const float4*)(ws + (size_t)2 * QS + i);
  const float4 d = *(const float4*)(ws + (size_t)3 * QS + i);
  float4 o;
  o.x = (a.x + b.x) + (c.x + d.x);
  o.y = (a.y + b.y) + (c.y + d.y);
  o.z = (a.z + b.z) + (c.z + d.z);
  o.w = (a.w + b.w) + (c.w + d.w);
  *(float4*)(out + i) = o;
}

// ---- fallback (known-good R2 kernel, used only if ws_size < 42.5 MB) ----
__global__ __launch_bounds__(64)
void costvol_fallback(const float* __restrict__ src,
                      const float* __restrict__ tgt,
                      float* __restrict__ out) {
  const int lane = threadIdx.x;
  const int slice = blockIdx.x >> 5;
  const int di = slice % ND;
  const int b  = slice / ND;
  const int h  = ((blockIdx.x & 31) << 1) + (lane >> 5);
  const int w0 = (lane & 31) << 2;
  const int y  = h + di - 8;

  float acc[ND][4];
#pragma unroll
  for (int dj = 0; dj < ND; ++dj)
#pragma unroll
    for (int k = 0; k < 4; ++k) acc[dj][k] = 0.0f;

  const bool q0 = w0 >= 8;
  const bool q1 = w0 >= 4;

  if (y >= 0) {
    const float* spc = src + (size_t)((b * NC) * NH + h) * NW + w0;
    const float* tpc = tgt + (size_t)((b * NC) * NH + y) * NW;
#pragma unroll 4
    for (int c = 0; c < NC; ++c) {
      const float4 sv = *(const float4*)spc;
      float t[12];
      float4 t0 = q0 ? *(const float4*)(tpc + w0 - 8) : make_float4(0.f, 0.f, 0.f, 0.f);
      float4 t1 = q1 ? *(const float4*)(tpc + w0 - 4) : make_float4(0.f, 0.f, 0.f, 0.f);
      float4 t2 = *(const float4*)(tpc + w0);
      t[0] = t0.x; t[1] = t0.y; t[2]  = t0.z; t[3]  = t0.w;
      t[4] = t1.x; t[5] = t1.y; t[6]  = t1.z; t[7]  = t1.w;
      t[8] = t2.x; t[9] = t2.y; t[10] = t2.z; t[11] = t2.w;
#pragma unroll
      for (int dj = 0; dj < ND; ++dj) {
        acc[dj][0] = fmaf(sv.x, t[dj + 0], acc[dj][0]);
        acc[dj][1] = fmaf(sv.y, t[dj + 1], acc[dj][1]);
        acc[dj][2] = fmaf(sv.z, t[dj + 2], acc[dj][2]);
        acc[dj][3] = fmaf(sv.w, t[dj + 3], acc[dj][3]);
      }
      spc += HW;
      tpc += HW;
    }
  }
#pragma unroll
  for (int dj = 0; dj < ND; ++dj) {
    float4 o;
    o.x = acc[dj][0]; o.y = acc[dj][1]; o.z = acc[dj][2]; o.w = acc[dj][3];
    *(float4*)(out + (size_t)(((b * NOUT + di * ND + dj) * NH + h) * NW + w0)) = o;
  }
}

extern "C" void kernel_launch(void* const* d_in, const int* in_sizes, int n_in,
                              void* d_out, int out_size, void* d_ws, size_t ws_size,
                              hipStream_t stream) {
  const float* src = (const float*)d_in[0];
  const float* tgt = (const float*)d_in[1];
  float* out = (float*)d_out;
  if (ws_size >= (size_t)NQ * QS * sizeof(float)) {
    float* ws = (float*)d_ws;
    costvol_stage1<<<dim3(256), dim3(576), 0, stream>>>(src, tgt, ws);
    costvol_reduce<<<dim3(QS / 1024), dim3(256), 0, stream>>>(ws, out);
  } else {
    costvol_fallback<<<dim3(NB * ND * 32), dim3(64), 0, stream>>>(src, tgt, out);
  }
}

// Round 7
// 105.345 us; speedup vs baseline: 3.6013x; 1.2957x over previous
//
#include <hip/hip_runtime.h>
#include <stdint.h>

// (B,C,H,W)=(4,128,64,128), R=4, D=9, out channels 81.
// out[b, di*9+dj, h, w] = sum_c src[b,c,h,w] * tgt[b,c,h+di-8,w+dj-8]
// (zero when shifted index leaves [0,H)x[0,W)).
//
// Stage1 (barrier-free, no LDS): threads organized around TGT row y.
//   Thread = (b, cq, y, s, wq): holds tgt window cols [4wq-8, 4wq+4) of row y
//   (12 floats, reused across all 9 dj) and 3 src quads of rows h=y+3s+j
//   (j=0..2 -> di=8-3s-j). acc[3][9][4] = 108 independent FMA chains.
//   Per channel: 6 dwordx4 loads -> 108 FMAs (2.25 FLOP/B logical).
//   512 blocks x 192 thr (3 waves, wave==s); cq = 32-channel quarter.
//   Partials stored to ws with plain float4 stores (no atomics).
// Stage2: out = sum of 4 quarters; slots with h+di<8 are written as zero
//   (stage1 never writes them).
#define NB 4
#define NC 128
#define NH 64
#define NW 128
#define HW (NH * NW)
#define ND 9
#define NOUT 81
#define NQ 4
#define CQ 32
#define QS (NB * NOUT * HW)   // 2,654,208 floats per quarter

__global__ __launch_bounds__(192)
void costvol_stage1(const float* __restrict__ src,
                    const float* __restrict__ tgt,
                    float* __restrict__ ws) {
  const int tid  = threadIdx.x;
  const int s    = tid >> 6;            // 0..2 (wave id = di-group)
  const int lane = tid & 63;
  const int bid  = blockIdx.x;
  const int bc   = bid & 15;            // (b*4+cq) -> XCD = bc%8 (L2 locality)
  const int b    = bc >> 2;
  const int cq   = bc & 3;
  const int y    = ((bid >> 4) << 1) + (lane >> 5);  // tgt row 0..63 (always valid)
  const int wq   = lane & 31;
  const int w0   = wq << 2;             // 0,4,...,124
  const int h0   = y + 3 * s;           // src row for j=0 (may exceed 63)

  // Left-edge predicates (per-quad all-or-nothing); clamp addr, select zero.
  const bool q0 = (wq >= 2);
  const bool q1 = (wq >= 1);
  const int ct0 = q0 ? (w0 - 8) : 0;
  const int ct1 = q1 ? (w0 - 4) : 0;

  // Clamp OOB src rows to row 0: loaded garbage accumulates into acc[j]
  // that is never stored (h>=NH skips the store), so no zeroing needed.
  const int r0 = (h0 + 0 < NH) ? (h0 + 0) : 0;
  const int r1 = (h0 + 1 < NH) ? (h0 + 1) : 0;
  const int r2 = (h0 + 2 < NH) ? (h0 + 2) : 0;

  const size_t base = (size_t)(b * NC + cq * CQ) * HW;
  const float* tp  = tgt + base + (size_t)y  * NW;
  const float* sp0 = src + base + (size_t)r0 * NW + w0;
  const float* sp1 = src + base + (size_t)r1 * NW + w0;
  const float* sp2 = src + base + (size_t)r2 * NW + w0;

  float acc[3][ND][4];
#pragma unroll
  for (int j = 0; j < 3; ++j)
#pragma unroll
    for (int dj = 0; dj < ND; ++dj)
#pragma unroll
      for (int p = 0; p < 4; ++p) acc[j][dj][p] = 0.0f;

#pragma unroll 2
  for (int c = 0; c < CQ; ++c) {
    float4 t0 = *(const float4*)(tp + ct0);
    float4 t1 = *(const float4*)(tp + ct1);
    const float4 t2 = *(const float4*)(tp + w0);   // cols 4wq..4wq+3, in-bounds
    const float4 s0 = *(const float4*)sp0;
    const float4 s1 = *(const float4*)sp1;
    const float4 s2 = *(const float4*)sp2;
    if (!q0) { t0.x = 0.f; t0.y = 0.f; t0.z = 0.f; t0.w = 0.f; }
    if (!q1) { t1.x = 0.f; t1.y = 0.f; t1.z = 0.f; t1.w = 0.f; }

    float T[12];
    T[0] = t0.x; T[1] = t0.y; T[2]  = t0.z; T[3]  = t0.w;
    T[4] = t1.x; T[5] = t1.y; T[6]  = t1.z; T[7]  = t1.w;
    T[8] = t2.x; T[9] = t2.y; T[10] = t2.z; T[11] = t2.w;
    const float S0[4] = {s0.x, s0.y, s0.z, s0.w};
    const float S1[4] = {s1.x, s1.y, s1.z, s1.w};
    const float S2[4] = {s2.x, s2.y, s2.z, s2.w};

#pragma unroll
    for (int dj = 0; dj < ND; ++dj) {
#pragma unroll
      for (int p = 0; p < 4; ++p) {
        acc[0][dj][p] = fmaf(S0[p], T[p + dj], acc[0][dj][p]);
        acc[1][dj][p] = fmaf(S1[p], T[p + dj], acc[1][dj][p]);
        acc[2][dj][p] = fmaf(S2[p], T[p + dj], acc[2][dj][p]);
      }
    }

    tp += HW; sp0 += HW; sp1 += HW; sp2 += HW;
  }

  // Epilogue: store valid rows' partials. Slot (b,cq,di,dj,h,w) is unique to
  // this thread (y = h+di-8), so plain stores suffice.
  const int dibase = 8 - 3 * s;
#pragma unroll
  for (int j = 0; j < 3; ++j) {
    const int h = h0 + j;
    if (h < NH) {
      const int di = dibase - j;
      float* op = ws + (size_t)cq * QS
                + (size_t)((b * NOUT + di * ND) * NH + h) * NW + w0;
#pragma unroll
      for (int dj = 0; dj < ND; ++dj) {
        float4 o;
        o.x = acc[j][dj][0]; o.y = acc[j][dj][1];
        o.z = acc[j][dj][2]; o.w = acc[j][dj][3];
        *(float4*)(op + (size_t)dj * HW) = o;
      }
    }
  }
}

// out = sum of 4 quarter partials; h+di<8 slots are pure zeros (never written
// by stage1 -> must not be read). grid = 663552/256 = 2592 blocks exactly.
__global__ __launch_bounds__(256)
void costvol_stage2(const float* __restrict__ ws, float* __restrict__ out) {
  const int i4 = blockIdx.x * 256 + threadIdx.x;  // float4 index < 663552
  const size_t i = (size_t)i4 * 4;
  const int h   = (i4 >> 5) & 63;
  const int t   = i4 >> 11;        // b*81 + (di*9+dj), < 324
  const int c81 = t % 81;
  const int di  = c81 / 9;
  float4 o = make_float4(0.f, 0.f, 0.f, 0.f);
  if (h + di >= 8) {
    const float4 a = *(const float4*)(ws + i);
    const float4 b4 = *(const float4*)(ws + (size_t)QS + i);
    const float4 c4 = *(const float4*)(ws + (size_t)2 * QS + i);
    const float4 d4 = *(const float4*)(ws + (size_t)3 * QS + i);
    o.x = (a.x + b4.x) + (c4.x + d4.x);
    o.y = (a.y + b4.y) + (c4.y + d4.y);
    o.z = (a.z + b4.z) + (c4.z + d4.z);
    o.w = (a.w + b4.w) + (c4.w + d4.w);
  }
  *(float4*)(out + i) = o;
}

// ---- fallback (known-good R2 kernel) if ws is ever too small ----
__global__ __launch_bounds__(64)
void costvol_fallback(const float* __restrict__ src,
                      const float* __restrict__ tgt,
                      float* __restrict__ out) {
  const int lane = threadIdx.x;
  const int slice = blockIdx.x >> 5;
  const int di = slice % ND;
  const int b  = slice / ND;
  const int h  = ((blockIdx.x & 31) << 1) + (lane >> 5);
  const int w0 = (lane & 31) << 2;
  const int y  = h + di - 8;

  float acc[ND][4];
#pragma unroll
  for (int dj = 0; dj < ND; ++dj)
#pragma unroll
    for (int k = 0; k < 4; ++k) acc[dj][k] = 0.0f;

  const bool q0 = w0 >= 8;
  const bool q1 = w0 >= 4;

  if (y >= 0) {
    const float* spc = src + (size_t)((b * NC) * NH + h) * NW + w0;
    const float* tpc = tgt + (size_t)((b * NC) * NH + y) * NW;
#pragma unroll 4
    for (int c = 0; c < NC; ++c) {
      const float4 sv = *(const float4*)spc;
      float t[12];
      float4 t0 = q0 ? *(const float4*)(tpc + w0 - 8) : make_float4(0.f, 0.f, 0.f, 0.f);
      float4 t1 = q1 ? *(const float4*)(tpc + w0 - 4) : make_float4(0.f, 0.f, 0.f, 0.f);
      float4 t2 = *(const float4*)(tpc + w0);
      t[0] = t0.x; t[1] = t0.y; t[2]  = t0.z; t[3]  = t0.w;
      t[4] = t1.x; t[5] = t1.y; t[6]  = t1.z; t[7]  = t1.w;
      t[8] = t2.x; t[9] = t2.y; t[10] = t2.z; t[11] = t2.w;
#pragma unroll
      for (int dj = 0; dj < ND; ++dj) {
        acc[dj][0] = fmaf(sv.x, t[dj + 0], acc[dj][0]);
        acc[dj][1] = fmaf(sv.y, t[dj + 1], acc[dj][1]);
        acc[dj][2] = fmaf(sv.z, t[dj + 2], acc[dj][2]);
        acc[dj][3] = fmaf(sv.w, t[dj + 3], acc[dj][3]);
      }
      spc += HW;
      tpc += HW;
    }
  }
#pragma unroll
  for (int dj = 0; dj < ND; ++dj) {
    float4 o;
    o.x = acc[dj][0]; o.y = acc[dj][1]; o.z = acc[dj][2]; o.w = acc[dj][3];
    *(float4*)(out + (size_t)(((b * NOUT + di * ND + dj) * NH + h) * NW + w0)) = o;
  }
}

extern "C" void kernel_launch(void* const* d_in, const int* in_sizes, int n_in,
                              void* d_out, int out_size, void* d_ws, size_t ws_size,
                              hipStream_t stream) {
  const float* src = (const float*)d_in[0];
  const float* tgt = (const float*)d_in[1];
  float* out = (float*)d_out;
  if (ws_size >= (size_t)NQ * QS * sizeof(float)) {
    float* ws = (float*)d_ws;
    costvol_stage1<<<dim3(512), dim3(192), 0, stream>>>(src, tgt, ws);
    costvol_stage2<<<dim3(QS / 1024), dim3(256), 0, stream>>>(ws, out);
  } else {
    costvol_fallback<<<dim3(NB * ND * 32), dim3(64), 0, stream>>>(src, tgt, out);
  }
}